// Round 3
// baseline (761.577 us; speedup 1.0000x reference)
//
#include <hip/hip_runtime.h>
#include <stdint.h>

// W4A16 dequant-GEMM for MI355X (gfx950).
// Harness dtype contract (fp16 reference is normalized): X fp32 [8192][4096],
// W int32 [11008][2048] (ONE byte = 2 int4 per int32 element), S fp32 [11008][32],
// Y fp32 [8192][11008].
//
// Fast path (ws_size >= 157.3 MB): cvt_x (X->bf16) + cvt_w (dequant W->bf16) into d_ws,
// then pure-bf16 GEMM: BM=256 BN=128 BK=64, 512 thr = 8 waves (4Mx2N), 64x64/wave,
// mfma_f32_16x16x32_bf16, global_load_lds(16B) with pre-swizzled source (XOR st-swizzle).
// Fallback: fused reg-staged convert/dequant, same tile + fragment + epilogue.

namespace {

typedef unsigned int u32;
typedef unsigned short u16;
typedef __attribute__((ext_vector_type(8))) short bf16x8;   // 8 bf16 = 4 VGPR
typedef __attribute__((ext_vector_type(4))) float f32x4;
typedef __attribute__((ext_vector_type(4))) u32 u32x4;

constexpr int Mt = 8192;
constexpr int Nt = 11008;
constexpr int Kt = 4096;
constexpr int KP = Kt / 2;    // int32 per W row (each int32 holds ONE byte = 2 nibbles)
constexpr int NG = 32;        // scale groups (K/128)
constexpr int BM = 256;
constexpr int BN = 128;
constexpr int BK = 64;
constexpr int THREADS = 512;
constexpr int GRID = (Mt / BM) * (Nt / BN);  // 32 * 86 = 2752 (divisible by 8)
constexpr int NKT = Kt / BK;                 // 64
constexpr int NB_CNT = Nt / BN;              // 86

__device__ __forceinline__ u16 f2bf(float f) {   // RNE f32 -> bf16 bits
  u32 u = __float_as_uint(f);
  return (u16)((u + 0x7FFFu + ((u >> 16) & 1u)) >> 16);
}
__device__ __forceinline__ u32 pk2bf(float a, float b) {
  return (u32)f2bf(a) | ((u32)f2bf(b) << 16);
}
// One byte (2 int4, low nibble = even k) -> 2 bf16 packed in one u32.
__device__ __forceinline__ u32 dqpair(u32 b, float s, float c) {
  float f0 = (float)(b & 15u);
  float f1 = (float)((b >> 4) & 15u);
  return pk2bf(fmaf(f0, s, c), fmaf(f1, s, c));
}
__device__ __forceinline__ void async16(const void* g, void* l) {
  __builtin_amdgcn_global_load_lds(
      (const __attribute__((address_space(1))) u32*)g,
      (__attribute__((address_space(3))) u32*)l, 16, 0, 0);
}

// ---- one-shot converters (HBM-bound, ~40 us total) ----
__global__ __launch_bounds__(256) void cvt_x(const float* __restrict__ X,
                                             u32* __restrict__ O) {
  const int total = Mt * Kt / 4;
  for (int j = blockIdx.x * 256 + threadIdx.x; j < total;
       j += (int)(gridDim.x * 256)) {
    float4 v = ((const float4*)X)[j];
    ((uint2*)O)[j] = make_uint2(pk2bf(v.x, v.y), pk2bf(v.z, v.w));
  }
}

__global__ __launch_bounds__(256) void cvt_w(const int* __restrict__ W,
                                             const float* __restrict__ S,
                                             u32* __restrict__ O) {
  const int total = Nt * KP / 4;
  for (int j = blockIdx.x * 256 + threadIdx.x; j < total;
       j += (int)(gridDim.x * 256)) {
    int4 v = ((const int4*)W)[j];
    int vv[4] = {v.x, v.y, v.z, v.w};
    const int j0 = j * 4;            // flat int32 index = row*2048 + jj
    const int row = j0 >> 11;
    const int jj = j0 & 2047;
    const float* sr = S + (size_t)row * NG;
    u32x4 o;
    #pragma unroll
    for (int e = 0; e < 4; ++e) {
      float s = sr[(jj + e) >> 6];   // k-group = (2*jj)/128 = jj/64
      o[e] = dqpair((u32)vv[e], s, -8.f * s);
    }
    ((u32x4*)O)[j] = o;              // u32 index jj holds k=2jj (lo), 2jj+1 (hi)
  }
}

// ---- GEMM ----
template <bool PRE>
__global__ __launch_bounds__(THREADS) void gemm(
    const float* __restrict__ Xf, const int* __restrict__ W,
    const float* __restrict__ S, const u16* __restrict__ Xb,
    const u16* __restrict__ Wb, float* __restrict__ Y) {
  __shared__ __align__(16) unsigned char Alds[BM * BK * 2];  // 32 KiB
  __shared__ __align__(16) unsigned char Blds[BN * BK * 2];  // 16 KiB

  const int tid = (int)threadIdx.x;
  const int lane = tid & 63;
  const int wid = tid >> 6;
  const int wm = wid >> 1;   // 0..3
  const int wn = wid & 1;    // 0..1

  // XCD-bijective swizzle; nb fast-varying so each XCD keeps its X panel (2 MB)
  // L2-resident while W streams.
  const int bid = (int)blockIdx.x;
  const int wg = (bid & 7) * (GRID / 8) + (bid >> 3);
  const int mb = wg / NB_CNT;
  const int nb = wg - mb * NB_CNT;
  const int m0 = mb * BM;
  const int n0 = nb * BN;

  // fragment-read constants: A row m=(lane&15), k=kk*32+(lane>>4)*8 contiguous;
  // physical 16B slot = logical ^ (row&7), row&7 == lane&7.
  const int frow = lane & 15;
  const int fk = lane >> 4;
  const int fswz = (lane & 7) << 4;
  const unsigned char* aRd = Alds + (wm * 64 + frow) * 128;
  const unsigned char* bRd = Blds + (wn * 64 + frow) * 128;

  f32x4 acc[4][4];
  #pragma unroll
  for (int i = 0; i < 4; ++i)
    #pragma unroll
    for (int j = 0; j < 4; ++j) acc[i][j] = f32x4{0.f, 0.f, 0.f, 0.f};

  // --- PRE staging: global_load_lds, pre-swizzled per-lane SOURCE, linear dest ---
  const int lrow = lane >> 3, lslot = lane & 7;
  const int psl = lslot ^ (lrow & 7);
  const u16* aG = PRE ? Xb + (size_t)(m0 + wid * 32 + lrow) * Kt + psl * 8 : nullptr;
  const u16* bG = PRE ? Wb + (size_t)(n0 + wid * 16 + lrow) * Kt + psl * 8 : nullptr;
  unsigned char* aL = Alds + (wid * 32) * 128;
  unsigned char* bL = Blds + (wid * 16) * 128;

  // --- FUSED staging constants ---
  const int arow = tid >> 3, acol = tid & 7;          // A: row, logical slot
  const float* fA = PRE ? nullptr : Xf + (size_t)(m0 + arow) * Kt + acol * 8;
  unsigned char* fAD = Alds + arow * 128 + ((acol ^ (arow & 7)) << 4);
  const int nloc = tid >> 3, c4 = tid & 7;            // B: row, logical slot
  const int* fB0 = PRE ? nullptr : W + (size_t)(n0 + nloc) * KP + c4 * 4;
  const int* fB1 = PRE ? nullptr : fB0 + (size_t)64 * KP;
  const float* sp0 = PRE ? nullptr : S + (size_t)(n0 + nloc) * NG;
  const float* sp1 = PRE ? nullptr : sp0 + (size_t)64 * NG;
  unsigned char* fBD0 = Blds + nloc * 128 + ((c4 ^ (nloc & 7)) << 4);
  unsigned char* fBD1 = fBD0 + 64 * 128;

  #pragma unroll 1
  for (int kt = 0; kt < NKT; ++kt) {
    const int k0 = kt * BK;

    if constexpr (PRE) {
      #pragma unroll
      for (int i = 0; i < 4; ++i) async16(aG + (size_t)i * 8 * Kt + k0, aL + i * 1024);
      #pragma unroll
      for (int j = 0; j < 2; ++j) async16(bG + (size_t)j * 8 * Kt + k0, bL + j * 1024);
    } else {
      #pragma unroll
      for (int p = 0; p < 4; ++p) {
        float4 x0 = *(const float4*)(fA + (size_t)p * 64 * Kt + k0);
        float4 x1 = *(const float4*)(fA + (size_t)p * 64 * Kt + k0 + 4);
        u32x4 q;
        q[0] = pk2bf(x0.x, x0.y); q[1] = pk2bf(x0.z, x0.w);
        q[2] = pk2bf(x1.x, x1.y); q[3] = pk2bf(x1.z, x1.w);
        *(u32x4*)(fAD + p * 64 * 128) = q;
      }
      const int g = k0 >> 7;
      const float s0 = sp0[g], s1 = sp1[g];
      const float c0 = -8.f * s0, c1 = -8.f * s1;
      const int4 w0 = *(const int4*)(fB0 + (k0 >> 1));
      const int4 w1 = *(const int4*)(fB1 + (k0 >> 1));
      u32x4 q0, q1;
      q0[0] = dqpair((u32)w0.x, s0, c0); q0[1] = dqpair((u32)w0.y, s0, c0);
      q0[2] = dqpair((u32)w0.z, s0, c0); q0[3] = dqpair((u32)w0.w, s0, c0);
      q1[0] = dqpair((u32)w1.x, s1, c1); q1[1] = dqpair((u32)w1.y, s1, c1);
      q1[2] = dqpair((u32)w1.z, s1, c1); q1[3] = dqpair((u32)w1.w, s1, c1);
      *(u32x4*)fBD0 = q0;
      *(u32x4*)fBD1 = q1;
    }

    __syncthreads();   // drains vmcnt (global_load_lds) / lgkmcnt (ds_write)

    #pragma unroll
    for (int kk = 0; kk < 2; ++kk) {
      const int koff = (kk * 64 + fk * 16) ^ fswz;
      bf16x8 af[4], bfr[4];
      #pragma unroll
      for (int fm = 0; fm < 4; ++fm)
        af[fm] = *(const bf16x8*)(aRd + fm * 16 * 128 + koff);
      #pragma unroll
      for (int fn = 0; fn < 4; ++fn)
        bfr[fn] = *(const bf16x8*)(bRd + fn * 16 * 128 + koff);
      #pragma unroll
      for (int fm = 0; fm < 4; ++fm)
        #pragma unroll
        for (int fn = 0; fn < 4; ++fn)
          acc[fm][fn] = __builtin_amdgcn_mfma_f32_16x16x32_bf16(
              af[fm], bfr[fn], acc[fm][fn], 0, 0, 0);
    }

    __syncthreads();   // protect LDS against next iteration's writes
  }

  // Epilogue: C/D mapping col = lane&15, row = (lane>>4)*4 + reg (m89/m91). f32 out.
  #pragma unroll
  for (int fm = 0; fm < 4; ++fm) {
    #pragma unroll
    for (int r = 0; r < 4; ++r) {
      const size_t mrow = (size_t)(m0 + wm * 64 + fm * 16 + fk * 4 + r) * Nt;
      #pragma unroll
      for (int fn = 0; fn < 4; ++fn) {
        Y[mrow + (size_t)(n0 + wn * 64 + fn * 16 + frow)] = acc[fm][fn][r];
      }
    }
  }
}

}  // namespace

extern "C" void kernel_launch(void* const* d_in, const int* in_sizes, int n_in,
                              void* d_out, int out_size, void* d_ws, size_t ws_size,
                              hipStream_t stream) {
  (void)in_sizes; (void)n_in; (void)out_size;
  const float* X = (const float*)d_in[0];
  const int* W   = (const int*)d_in[1];
  const float* S = (const float*)d_in[2];
  float* Y       = (float*)d_out;

  const size_t xbytes = (size_t)Mt * Kt * 2;   // 67,108,864
  const size_t wbytes = (size_t)Nt * Kt * 2;   // 90,177,536

  if (ws_size >= xbytes + wbytes) {
    u16* Xb = (u16*)d_ws;
    u16* Wb = (u16*)((char*)d_ws + xbytes);
    cvt_x<<<dim3(2048), dim3(256), 0, stream>>>(X, (u32*)Xb);
    cvt_w<<<dim3(2048), dim3(256), 0, stream>>>(W, S, (u32*)Wb);
    gemm<true><<<dim3(GRID), dim3(THREADS), 0, stream>>>(nullptr, nullptr, nullptr,
                                                         Xb, Wb, Y);
  } else {
    gemm<false><<<dim3(GRID), dim3(THREADS), 0, stream>>>(X, W, S, nullptr, nullptr, Y);
  }
}